// Round 1
// baseline (847.955 us; speedup 1.0000x reference)
//
#include <hip/hip_runtime.h>
#include <hip/hip_bf16.h>

#define NLAT 721
#define NLON 1440
#define NB 8

// One thread per query point. Uniform-grid index math for lon (bit-exact vs
// searchsorted, see analysis); analytic index + fixup against the real
// lat_src array (LDS-staged) for lat. 8 batch values gathered per point,
// written as two coalesced float4.
__global__ __launch_bounds__(256) void regrid_kernel(
    const float* __restrict__ x,        // [NB, NLAT, NLON]
    const float* __restrict__ lat_src,  // [NLAT]
    const float* __restrict__ xi,       // [N, 2]
    float* __restrict__ out,            // [N, NB]
    int N)
{
    __shared__ float s_lat[NLAT];
    for (int t = threadIdx.x; t < NLAT; t += blockDim.x) s_lat[t] = lat_src[t];
    __syncthreads();

    int n = blockIdx.x * blockDim.x + threadIdx.x;
    if (n >= N) return;

    float2 q = ((const float2*)xi)[n];
    float lon = q.x;
    float lat = q.y;

    // ---- longitude: exact uniform-grid searchsorted ----
    float lon4 = lon * 4.0f;                 // exact (power-of-2 multiply)
    int i = (int)floorf(lon4);
    i = min(max(i, 0), NLON - 1);
    float wlon = lon4 - (float)i;            // == (lon - long[i]) / 0.25, exact
    int i1 = (i == NLON - 1) ? 0 : i + 1;    // periodic wrap column

    // ---- latitude: analytic index + fixup against actual array ----
    int j = (int)floorf((lat + 90.0f) * 4.0f);
    j = min(max(j, 0), NLAT - 2);
    while (j > 0 && lat < s_lat[j]) --j;
    while (j < NLAT - 2 && lat >= s_lat[j + 1]) ++j;
    float l0 = s_lat[j];
    float l1 = s_lat[j + 1];
    float wlat = (lat - l0) / (l1 - l0);
    float alat = 1.0f - wlat;
    float alon = 1.0f - wlon;

    float res[NB];
#pragma unroll
    for (int b = 0; b < NB; ++b) {
        const float* row0 = x + ((size_t)b * NLAT + j) * NLON;
        const float* row1 = row0 + NLON;
        float v00 = row0[i];
        float v10 = row0[i1];
        float v01 = row1[i];
        float v11 = row1[i1];
        res[b] = alat * (alon * v00 + wlon * v10)
               + wlat * (alon * v01 + wlon * v11);
    }

    float4* o = (float4*)(out + (size_t)n * NB);
    o[0] = make_float4(res[0], res[1], res[2], res[3]);
    o[1] = make_float4(res[4], res[5], res[6], res[7]);
}

extern "C" void kernel_launch(void* const* d_in, const int* in_sizes, int n_in,
                              void* d_out, int out_size, void* d_ws, size_t ws_size,
                              hipStream_t stream) {
    const float* x       = (const float*)d_in[0];
    // d_in[1] = lon_src (unused: grid is analytic-exact in fp32)
    const float* lat_src = (const float*)d_in[2];
    const float* xi      = (const float*)d_in[3];
    float* out           = (float*)d_out;

    int N = in_sizes[3] / 2;   // xi is [N, 2]
    int block = 256;
    int grid = (N + block - 1) / block;
    regrid_kernel<<<grid, block, 0, stream>>>(x, lat_src, xi, out, N);
}

// Round 2
// 274.002 us; speedup vs baseline: 3.0947x; 3.0947x over previous
//
#include <hip/hip_runtime.h>
#include <hip/hip_bf16.h>

#define NLAT 721
#define NLON 1440
#define NB 8

// ---------------------------------------------------------------------------
// Pass 1: transpose x[b][j][i] -> xt[j][i][b] so all 8 batch values of a grid
// node are contiguous (32 B), and node (j,i+1) is the adjacent 32 B.
// One thread per (j,i): 8 coalesced-across-lane strided reads, one 32 B
// contiguous write per thread (fully coalesced across the wave).
// ---------------------------------------------------------------------------
__global__ __launch_bounds__(256) void transpose_kernel(
    const float* __restrict__ x,   // [NB, NLAT, NLON]
    float* __restrict__ xt)        // [NLAT, NLON, NB]
{
    int idx = blockIdx.x * blockDim.x + threadIdx.x;   // j*NLON + i
    if (idx >= NLAT * NLON) return;

    float v[NB];
#pragma unroll
    for (int b = 0; b < NB; ++b)
        v[b] = x[(size_t)b * (NLAT * NLON) + idx];

    float4* o = (float4*)(xt + (size_t)idx * NB);
    o[0] = make_float4(v[0], v[1], v[2], v[3]);
    o[1] = make_float4(v[4], v[5], v[6], v[7]);
}

// ---------------------------------------------------------------------------
// Pass 2: gather + bilinear. Per point: 8x global_load_dwordx4 from xt
// (corners (j,i)&(j,i+1) are 64 contiguous bytes), two float4 stores.
// ---------------------------------------------------------------------------
__global__ __launch_bounds__(256) void regrid_xt_kernel(
    const float* __restrict__ xt,       // [NLAT, NLON, NB]
    const float* __restrict__ lat_src,  // [NLAT]
    const float* __restrict__ xi,       // [N, 2]
    float* __restrict__ out,            // [N, NB]
    int N)
{
    __shared__ float s_lat[NLAT];
    for (int t = threadIdx.x; t < NLAT; t += blockDim.x) s_lat[t] = lat_src[t];
    __syncthreads();

    int n = blockIdx.x * blockDim.x + threadIdx.x;
    if (n >= N) return;

    float2 q = ((const float2*)xi)[n];
    float lon = q.x;
    float lat = q.y;

    // longitude: exact uniform-grid searchsorted
    float lon4 = lon * 4.0f;
    int i = (int)floorf(lon4);
    i = min(max(i, 0), NLON - 1);
    float wlon = lon4 - (float)i;
    int i1 = (i == NLON - 1) ? 0 : i + 1;   // periodic wrap

    // latitude: analytic index + fixup against actual linspace values
    int j = (int)floorf((lat + 90.0f) * 4.0f);
    j = min(max(j, 0), NLAT - 2);
    while (j > 0 && lat < s_lat[j]) --j;
    while (j < NLAT - 2 && lat >= s_lat[j + 1]) ++j;
    float l0 = s_lat[j];
    float l1 = s_lat[j + 1];
    float wlat = (lat - l0) / (l1 - l0);
    float alat = 1.0f - wlat;
    float alon = 1.0f - wlon;

    size_t b00 = ((size_t)j * NLON + i) * NB;    // row j,  col i
    size_t b10 = ((size_t)j * NLON + i1) * NB;   // row j,  col i1
    size_t b01 = b00 + (size_t)NLON * NB;        // row j+1
    size_t b11 = b10 + (size_t)NLON * NB;

    const float4* p = (const float4*)xt;
    float4 v00a = p[b00 / 4],     v00b = p[b00 / 4 + 1];
    float4 v10a = p[b10 / 4],     v10b = p[b10 / 4 + 1];
    float4 v01a = p[b01 / 4],     v01b = p[b01 / 4 + 1];
    float4 v11a = p[b11 / 4],     v11b = p[b11 / 4 + 1];

    float w00 = alat * alon, w10 = alat * wlon;
    float w01 = wlat * alon, w11 = wlat * wlon;

    float4 ra, rb;
    ra.x = w00 * v00a.x + w10 * v10a.x + w01 * v01a.x + w11 * v11a.x;
    ra.y = w00 * v00a.y + w10 * v10a.y + w01 * v01a.y + w11 * v11a.y;
    ra.z = w00 * v00a.z + w10 * v10a.z + w01 * v01a.z + w11 * v11a.z;
    ra.w = w00 * v00a.w + w10 * v10a.w + w01 * v01a.w + w11 * v11a.w;
    rb.x = w00 * v00b.x + w10 * v10b.x + w01 * v01b.x + w11 * v11b.x;
    rb.y = w00 * v00b.y + w10 * v10b.y + w01 * v01b.y + w11 * v11b.y;
    rb.z = w00 * v00b.z + w10 * v10b.z + w01 * v01b.z + w11 * v11b.z;
    rb.w = w00 * v00b.w + w10 * v10b.w + w01 * v01b.w + w11 * v11b.w;

    float4* o = (float4*)(out + (size_t)n * NB);
    o[0] = ra;
    o[1] = rb;
}

// ---------------------------------------------------------------------------
// Fallback (R0 kernel) if workspace is too small for the transposed grid.
// ---------------------------------------------------------------------------
__global__ __launch_bounds__(256) void regrid_direct_kernel(
    const float* __restrict__ x,
    const float* __restrict__ lat_src,
    const float* __restrict__ xi,
    float* __restrict__ out,
    int N)
{
    __shared__ float s_lat[NLAT];
    for (int t = threadIdx.x; t < NLAT; t += blockDim.x) s_lat[t] = lat_src[t];
    __syncthreads();

    int n = blockIdx.x * blockDim.x + threadIdx.x;
    if (n >= N) return;

    float2 q = ((const float2*)xi)[n];
    float lon = q.x, lat = q.y;

    float lon4 = lon * 4.0f;
    int i = (int)floorf(lon4);
    i = min(max(i, 0), NLON - 1);
    float wlon = lon4 - (float)i;
    int i1 = (i == NLON - 1) ? 0 : i + 1;

    int j = (int)floorf((lat + 90.0f) * 4.0f);
    j = min(max(j, 0), NLAT - 2);
    while (j > 0 && lat < s_lat[j]) --j;
    while (j < NLAT - 2 && lat >= s_lat[j + 1]) ++j;
    float l0 = s_lat[j], l1 = s_lat[j + 1];
    float wlat = (lat - l0) / (l1 - l0);
    float alat = 1.0f - wlat, alon = 1.0f - wlon;

    float res[NB];
#pragma unroll
    for (int b = 0; b < NB; ++b) {
        const float* row0 = x + ((size_t)b * NLAT + j) * NLON;
        const float* row1 = row0 + NLON;
        res[b] = alat * (alon * row0[i] + wlon * row0[i1])
               + wlat * (alon * row1[i] + wlon * row1[i1]);
    }
    float4* o = (float4*)(out + (size_t)n * NB);
    o[0] = make_float4(res[0], res[1], res[2], res[3]);
    o[1] = make_float4(res[4], res[5], res[6], res[7]);
}

extern "C" void kernel_launch(void* const* d_in, const int* in_sizes, int n_in,
                              void* d_out, int out_size, void* d_ws, size_t ws_size,
                              hipStream_t stream) {
    const float* x       = (const float*)d_in[0];
    const float* lat_src = (const float*)d_in[2];
    const float* xi      = (const float*)d_in[3];
    float* out           = (float*)d_out;

    int N = in_sizes[3] / 2;
    const size_t xt_bytes = (size_t)NLAT * NLON * NB * sizeof(float);

    int block = 256;
    int grid = (N + block - 1) / block;

    if (ws_size >= xt_bytes) {
        float* xt = (float*)d_ws;
        int ngrid = (NLAT * NLON + block - 1) / block;
        transpose_kernel<<<ngrid, block, 0, stream>>>(x, xt);
        regrid_xt_kernel<<<grid, block, 0, stream>>>(xt, lat_src, xi, out, N);
    } else {
        regrid_direct_kernel<<<grid, block, 0, stream>>>(x, lat_src, xi, out, N);
    }
}